// Round 4
// baseline (242.277 us; speedup 1.0000x reference)
//
#include <hip/hip_runtime.h>
#include <hip/hip_bf16.h>

#define NN   5000
#define NP   5008          // NN padded to 16
#define NE   80000
#define HID  128
#define NRBF 64
#define PI_OVER_5 0.6283185307179586f
#define LN_EPS 1e-5f

typedef unsigned short bf16_t;
typedef __attribute__((ext_vector_type(8))) short short8;
typedef __attribute__((ext_vector_type(4))) float floatx4;

__device__ __forceinline__ bf16_t to_bf16(float x){
    union { float f; unsigned int u; } v; v.f = x;
    unsigned int r = v.u + 0x7fffu + ((v.u >> 16) & 1u);
    return (bf16_t)(r >> 16);
}
__device__ __forceinline__ float from_bf16(bf16_t h){
    union { unsigned int u; float f; } v; v.u = ((unsigned int)h) << 16;
    return v.f;
}
__device__ __forceinline__ uint4 pack8(const float* s){
    float4 a = *(const float4*)s;
    float4 b = *(const float4*)(s + 4);
    uint4 o;
    o.x = to_bf16(a.x) | ((unsigned)to_bf16(a.y) << 16);
    o.y = to_bf16(a.z) | ((unsigned)to_bf16(a.w) << 16);
    o.z = to_bf16(b.x) | ((unsigned)to_bf16(b.y) << 16);
    o.w = to_bf16(b.z) | ((unsigned)to_bf16(b.w) << 16);
    return o;
}
__device__ __forceinline__ short8 cvt8(float4 a, float4 b){
    short8 r;
    r[0] = (short)to_bf16(a.x); r[1] = (short)to_bf16(a.y);
    r[2] = (short)to_bf16(a.z); r[3] = (short)to_bf16(a.w);
    r[4] = (short)to_bf16(b.x); r[5] = (short)to_bf16(b.y);
    r[6] = (short)to_bf16(b.z); r[7] = (short)to_bf16(b.w);
    return r;
}

// ---------------------------------------------------------------- prep (weights + emb tables)
// blocks 0..99: pack Wd/Wt/Ws1/Ws2 -> bf16 (204800 bf16 elems, 8/thread)
// blocks 100..227: embL/embR[t][h] = W_emb2[h][(0|128)+k] . emb[t][k]
__global__ __launch_bounds__(256) void k_prep(
    const float* __restrict__ Wd1, const float* __restrict__ Wd2, const float* __restrict__ Wd3,
    const float* __restrict__ bd1, const float* __restrict__ bd2, const float* __restrict__ bd3,
    const float* __restrict__ Wt1, const float* __restrict__ Wt2, const float* __restrict__ Wt3,
    const float* __restrict__ Ws1, const float* __restrict__ Ws2,
    const float* __restrict__ W_emb2, const float* __restrict__ emb,
    bf16_t* __restrict__ Wcat, bf16_t* __restrict__ Wtc,
    bf16_t* __restrict__ Ws1b, bf16_t* __restrict__ Ws2b, float* __restrict__ bdcat,
    float* __restrict__ embL, float* __restrict__ embR)
{
    int b = blockIdx.x, tid = threadIdx.x;
    if (b < 100){
        int t = b * 256 + tid;
        int i8 = t * 8;
        const float* src; bf16_t* dst;
        if (i8 < 24576){
            int j = i8; int tb = j >> 13; int r = j & 8191;
            src = ((tb == 0) ? Wd1 : (tb == 1) ? Wd2 : Wd3) + r; dst = Wcat + j;
        } else if (i8 < 24576 + 49152){
            int j = i8 - 24576; int tb = j >> 14; int r = j & 16383;
            src = ((tb == 0) ? Wt1 : (tb == 1) ? Wt2 : Wt3) + r; dst = Wtc + j;
        } else if (i8 < 24576 + 49152 + 32768){
            int j = i8 - 73728; src = Ws1 + j; dst = Ws1b + j;
        } else {
            int j = i8 - 106496; src = Ws2 + j; dst = Ws2b + j;
        }
        *(uint4*)dst = pack8(src);
        if (t < 384){
            int tb2 = t >> 7, ch2 = t & 127;
            const float* bsrc = (tb2 == 0) ? bd1 : ((tb2 == 1) ? bd2 : bd3);
            bdcat[t] = bsrc[ch2];
        }
    } else {
        int t = b - 100;                 // atom type 0..127
        int half = tid >> 7;             // 0: embL, 1: embR
        int h = tid & 127;
        const float* wl = W_emb2 + (size_t)h * (2 * HID) + half * HID;
        const float* er = emb + t * HID;
        float s = 0.f;
        #pragma unroll 8
        for (int k = 0; k < HID; k++) s += wl[k] * er[k];
        (half ? embR : embL)[t * HID + h] = s;
    }
}

// ---------------------------------------------------------------- CSR build
__global__ void k_count(const int* __restrict__ ei, int* __restrict__ counts){
    int e = blockIdx.x * 256 + threadIdx.x;
    if (e < NE) atomicAdd(&counts[ei[e]], 1);
}

__global__ __launch_bounds__(1024) void k_scan(
    const int* __restrict__ counts, int* __restrict__ offsets, int* __restrict__ cursor)
{
    __shared__ int s[1024];
    const int t = threadIdx.x;
    const int CH = 5;
    int base = t * CH;
    int loc[CH];
    int lsum = 0;
    #pragma unroll
    for (int u = 0; u < CH; u++){
        int i = base + u;
        int v = (i < NN) ? counts[i] : 0;
        loc[u] = lsum;
        lsum += v;
    }
    s[t] = lsum;
    __syncthreads();
    for (int d = 1; d < 1024; d <<= 1){
        int v = (t >= d) ? s[t - d] : 0;
        __syncthreads();
        s[t] += v;
        __syncthreads();
    }
    int excl = s[t] - lsum;
    #pragma unroll
    for (int u = 0; u < CH; u++){
        int i = base + u;
        if (i < NN){ int o = excl + loc[u]; offsets[i] = o; cursor[i] = o; }
    }
    if (t == 1023) offsets[NN] = s[1023];
}

__global__ void k_fill(const int* __restrict__ ei, const int* __restrict__ z,
                       const float* __restrict__ ew, const float* __restrict__ evn,
                       int* __restrict__ cursor, int* __restrict__ elist,
                       float2* __restrict__ meta, float* __restrict__ evn_p){
    int e = blockIdx.x * 256 + threadIdx.x;
    if (e < NE){
        int sN = ei[e], dN = ei[NE + e];
        int p = atomicAdd(&cursor[sN], 1);
        elist[p] = e;
        float w = ew[e];
        float c = (w < 5.0f) ? 0.5f * (__cosf(w * PI_OVER_5) + 1.0f) : 0.0f;
        meta[p] = make_float2(c, __int_as_float(z[sN] | (z[dN] << 8)));
        evn_p[p*3+0] = evn[e*3+0];
        evn_p[p*3+1] = evn[e*3+1];
        evn_p[p*3+2] = evn[e*3+2];
    }
}

// ---------------------------------------------------------------- fused edge GEMM + segment-sum + LN
// One block per node. A = attr rows (edges -> D rows), B = Wcat (channels -> D cols).
// f_t(e,ch) = (D_t + bd_t) * cut_e * (embL[zs]+embR[zd]+b_emb2); 10 geometric planes
// accumulated per-lane over edge regs, shfl-reduced over q-groups, then LN in-block.
__global__ __launch_bounds__(256) void k_edge_gather(
    const int* __restrict__ offs, const int* __restrict__ elist,
    const float2* __restrict__ meta, const float* __restrict__ evn_p,
    const float* __restrict__ attr,
    const bf16_t* __restrict__ Wcat, const float* __restrict__ bdcat,
    const float* __restrict__ embL, const float* __restrict__ embR,
    const float* __restrict__ b_emb2,
    const float* __restrict__ ln_g, const float* __restrict__ ln_b,
    bf16_t* __restrict__ accb, bf16_t* __restrict__ lnb)
{
    __shared__ __align__(16) float4 sV[64];   // vx,vy,vz,cut per CSR slot in chunk
    __shared__ int   sZZ[64];                 // zs | zd<<8
    __shared__ float sAcc[10][132];
    __shared__ float sRed[8];

    const int tid = threadIdx.x;
    const int wv = tid >> 6, lane = tid & 63;
    const int col = lane & 15, q = lane >> 4;
    const int n = blockIdx.x;
    const int s = offs[n], e_end = offs[n + 1];

    // preload B-frags (Wcat, L2-resident) + biases; wave covers 3 tables x 32 ch
    short8 bfr[6][2];
    float bdv[3][2], bev[2];
    #pragma unroll
    for (int cg = 0; cg < 2; cg++){
        int ch = wv * 32 + cg * 16 + col;
        bev[cg] = b_emb2[ch];
        #pragma unroll
        for (int t = 0; t < 3; t++){
            bdv[t][cg] = bdcat[t * 128 + ch];
            #pragma unroll
            for (int s2 = 0; s2 < 2; s2++)
                bfr[t * 2 + cg][s2] = *(const short8*)(Wcat + (size_t)(t * 128 + ch) * NRBF + s2 * 32 + q * 8);
        }
    }

    float pl[10][2];
    #pragma unroll
    for (int p = 0; p < 10; p++){ pl[p][0] = 0.f; pl[p][1] = 0.f; }

    for (int c0 = s; c0 < e_end; c0 += 64){
        __syncthreads();   // protect sV/sZZ restage (WAR vs previous chunk)
        if (tid < 64){
            int pos = c0 + tid;
            if (pos < e_end){
                float2 m = meta[pos];
                sV[tid]  = make_float4(evn_p[pos*3+0], evn_p[pos*3+1], evn_p[pos*3+2], m.x);
                sZZ[tid] = __float_as_int(m.y);
            } else {
                sV[tid]  = make_float4(0.f, 0.f, 0.f, 0.f);
                sZZ[tid] = 0;
            }
        }
        __syncthreads();
        int nch = e_end - c0; if (nch > 64) nch = 64;
        int ntiles = (nch + 15) >> 4;
        for (int t16 = 0; t16 < ntiles; t16++){
            // A-frags: edge = t16*16 + col (m index), k = s2*32 + q*8 + j
            int pos = c0 + t16 * 16 + col;
            int cpos = (pos < e_end) ? pos : (e_end - 1);
            int e = elist[cpos];
            const float* ar = attr + (size_t)e * NRBF + q * 8;
            short8 af[2];
            #pragma unroll
            for (int s2 = 0; s2 < 2; s2++){
                float4 u0 = *(const float4*)(ar + s2 * 32);
                float4 u1 = *(const float4*)(ar + s2 * 32 + 4);
                af[s2] = cvt8(u0, u1);
            }
            // MFMA: D[row=edge q*4+r][col=ch]
            floatx4 D[3][2];
            #pragma unroll
            for (int t = 0; t < 3; t++)
                #pragma unroll
                for (int cg = 0; cg < 2; cg++){
                    floatx4 d = (floatx4)(0.f);
                    d = __builtin_amdgcn_mfma_f32_16x16x32_bf16(af[0], bfr[t*2+cg][0], d, 0, 0, 0);
                    d = __builtin_amdgcn_mfma_f32_16x16x32_bf16(af[1], bfr[t*2+cg][1], d, 0, 0, 0);
                    D[t][cg] = d;
                }
            // epilogue: per edge-reg r, build 10 plane contributions
            #pragma unroll
            for (int r = 0; r < 4; r++){
                int eslot = t16 * 16 + q * 4 + r;
                float4 vv = sV[eslot];
                int zp = sZZ[eslot];
                int zs = zp & 255, zd = zp >> 8;
                float vx = vv.x, vy = vv.y, vz = vv.z, cut = vv.w;
                float xx = vx*vx, yy = vy*vy, zz = vz*vz;
                float t3 = (xx + yy + zz) * (1.f/3.f);
                float gxx = xx - t3, gyy = yy - t3, gzz = zz - t3;
                float gxy = vx*vy, gxz = vx*vz, gyz = vy*vz;
                #pragma unroll
                for (int cg = 0; cg < 2; cg++){
                    int ch = wv * 32 + cg * 16 + col;
                    float L = embL[zs * HID + ch];
                    float R = embR[zd * HID + ch];
                    float Cv = cut * (L + R + bev[cg]);
                    float f1 = (D[0][cg][r] + bdv[0][cg]) * Cv;
                    float f2 = (D[1][cg][r] + bdv[1][cg]) * Cv;
                    float f3 = (D[2][cg][r] + bdv[2][cg]) * Cv;
                    pl[0][cg] += f1;
                    pl[1][cg] += f2 * vx; pl[2][cg] += f2 * vy; pl[3][cg] += f2 * vz;
                    pl[4][cg] += f3 * gxx; pl[5][cg] += f3 * gyy; pl[6][cg] += f3 * gzz;
                    pl[7][cg] += f3 * gxy; pl[8][cg] += f3 * gxz; pl[9][cg] += f3 * gyz;
                }
            }
        }
    }

    // reduce over q-groups (edges 0..15 of each tile summed): butterfly xor 16, 32
    #pragma unroll
    for (int p = 0; p < 10; p++)
        #pragma unroll
        for (int cg = 0; cg < 2; cg++){
            float v = pl[p][cg];
            v += __shfl_xor(v, 16);
            v += __shfl_xor(v, 32);
            pl[p][cg] = v;
        }
    if (lane < 16){
        #pragma unroll
        for (int p = 0; p < 10; p++){
            sAcc[p][wv * 32 + 0  + lane] = pl[p][0];
            sAcc[p][wv * 32 + 16 + lane] = pl[p][1];
        }
    }
    __syncthreads();

    // LayerNorm over channels
    float av[10]; float tn = 0.f;
    const int ch = tid;
    if (tid < 128){
        #pragma unroll
        for (int p = 0; p < 10; p++) av[p] = sAcc[p][ch];
        tn = 3.f*av[0]*av[0] + 2.f*av[0]*(av[4]+av[5]+av[6])
           + av[4]*av[4] + av[5]*av[5] + av[6]*av[6]
           + 2.f*(av[7]*av[7] + av[8]*av[8] + av[9]*av[9])
           + 2.f*(av[1]*av[1] + av[2]*av[2] + av[3]*av[3]);
    }
    float s1 = tn, s2 = tn * tn;
    #pragma unroll
    for (int d = 1; d < 64; d <<= 1){
        s1 += __shfl_xor(s1, d);
        s2 += __shfl_xor(s2, d);
    }
    if (lane == 0){ sRed[wv] = s1; sRed[4 + wv] = s2; }
    __syncthreads();
    if (tid < 128){
        float mu  = (sRed[0] + sRed[1]) * (1.f / HID);
        float var = (sRed[4] + sRed[5]) * (1.f / HID) - mu * mu;
        float ln = (tn - mu) * rsqrtf(var + LN_EPS) * ln_g[ch] + ln_b[ch];
        lnb[(size_t)n * HID + ch] = to_bf16(ln);
        #pragma unroll
        for (int p = 0; p < 10; p++)
            accb[(size_t)p * NP * HID + (size_t)n * HID + ch] = to_bf16(av[p]);
    }
}

// ---------------------------------------------------------------- fused node kernel
__global__ __launch_bounds__(256) void k_node(
    const bf16_t* __restrict__ lnb, const bf16_t* __restrict__ accb,
    const bf16_t* __restrict__ Ws1b, const float* __restrict__ bs1,
    const bf16_t* __restrict__ Ws2b, const float* __restrict__ bs2,
    const bf16_t* __restrict__ Wtc,
    float* __restrict__ out)
{
    __shared__ __align__(16) bf16_t h1s[16 * 280];
    __shared__ float nrms[16 * 392];

    const int tid = threadIdx.x;
    const int wv = tid >> 6, lane = tid & 63;
    const int col = lane & 15, q = lane >> 4;
    const int n0 = blockIdx.x * 16;

    // ---- phase 1: h1 = silu(lnb @ Ws1^T + bs1)
    {
        short8 a1[4];
        #pragma unroll
        for (int k = 0; k < 4; k++)
            a1[k] = *(const short8*)(lnb + (size_t)(n0 + col) * HID + k * 32 + q * 8);
        floatx4 c1[4];
        #pragma unroll
        for (int nt = 0; nt < 4; nt++) c1[nt] = (floatx4)(0.f);
        #pragma unroll
        for (int nt = 0; nt < 4; nt++){
            int cg = wv * 64 + nt * 16 + col;
            #pragma unroll
            for (int k = 0; k < 4; k++){
                short8 b = *(const short8*)(Ws1b + (size_t)cg * HID + k * 32 + q * 8);
                c1[nt] = __builtin_amdgcn_mfma_f32_16x16x32_bf16(a1[k], b, c1[nt], 0, 0, 0);
            }
        }
        #pragma unroll
        for (int nt = 0; nt < 4; nt++){
            int cg = wv * 64 + nt * 16 + col;
            float bias = bs1[cg];
            #pragma unroll
            for (int r = 0; r < 4; r++){
                float v = c1[nt][r] + bias;
                v = v / (1.f + __expf(-v));
                h1s[(q * 4 + r) * 280 + cg] = to_bf16(v);
            }
        }
    }
    __syncthreads();

    // ---- phase 2: norm = silu(h1 @ Ws2^T + bs2)
    {
        short8 a2[8];
        #pragma unroll
        for (int k = 0; k < 8; k++)
            a2[k] = *(const short8*)&h1s[col * 280 + k * 32 + q * 8];
        floatx4 c2[6];
        #pragma unroll
        for (int nt = 0; nt < 6; nt++) c2[nt] = (floatx4)(0.f);
        #pragma unroll
        for (int nt = 0; nt < 6; nt++){
            int cg = wv * 96 + nt * 16 + col;
            #pragma unroll
            for (int k = 0; k < 8; k++){
                short8 b = *(const short8*)(Ws2b + (size_t)cg * 256 + k * 32 + q * 8);
                c2[nt] = __builtin_amdgcn_mfma_f32_16x16x32_bf16(a2[k], b, c2[nt], 0, 0, 0);
            }
        }
        #pragma unroll
        for (int nt = 0; nt < 6; nt++){
            int cg = wv * 96 + nt * 16 + col;
            float bias = bs2[cg];
            #pragma unroll
            for (int r = 0; r < 4; r++){
                float v = c2[nt][r] + bias;
                v = v / (1.f + __expf(-v));
                nrms[(q * 4 + r) * 392 + cg] = v;
            }
        }
    }
    __syncthreads();

    // ---- phase 3: 10-plane mix GEMM + combine
    floatx4 cm[10][2];
    #pragma unroll
    for (int p = 0; p < 10; p++){
        #pragma unroll
        for (int nt = 0; nt < 2; nt++) cm[p][nt] = (floatx4)(0.f);
    }
    #pragma unroll
    for (int p = 0; p < 10; p++){
        const bf16_t* ap = accb + (size_t)p * NP * HID + (size_t)(n0 + col) * HID;
        short8 a3[4];
        #pragma unroll
        for (int k = 0; k < 4; k++)
            a3[k] = *(const short8*)(ap + k * 32 + q * 8);
        int tb = (p == 0) ? 0 : ((p < 4) ? 1 : 2);
        #pragma unroll
        for (int nt = 0; nt < 2; nt++){
            int g = wv * 32 + nt * 16 + col;
            const bf16_t* wp = Wtc + tb * 16384 + (size_t)g * HID;
            #pragma unroll
            for (int k = 0; k < 4; k++){
                short8 b = *(const short8*)(wp + k * 32 + q * 8);
                cm[p][nt] = __builtin_amdgcn_mfma_f32_16x16x32_bf16(a3[k], b, cm[p][nt], 0, 0, 0);
            }
        }
    }
    #pragma unroll
    for (int nt = 0; nt < 2; nt++){
        int g = wv * 32 + nt * 16 + col;
        #pragma unroll
        for (int r = 0; r < 4; r++){
            int node = q * 4 + r;
            int n = n0 + node;
            if (n < NN){
                float n0f = nrms[node * 392 + g * 3 + 0];
                float n1f = nrms[node * 392 + g * 3 + 1];
                float n2f = nrms[node * 392 + g * 3 + 2];
                float c   = cm[0][nt][r];
                float ax  = cm[1][nt][r], ay = cm[2][nt][r], az = cm[3][nt][r];
                float sxx = cm[4][nt][r], syy= cm[5][nt][r], szz= cm[6][nt][r];
                float sxy = cm[7][nt][r], sxz= cm[8][nt][r], syz= cm[9][nt][r];
                float* o = out + ((size_t)n * HID + g) * 9;
                o[0] = n0f*c + n2f*sxx;   o[1] = n2f*sxy - n1f*az;  o[2] = n2f*sxz + n1f*ay;
                o[3] = n2f*sxy + n1f*az;  o[4] = n0f*c + n2f*syy;   o[5] = n2f*syz - n1f*ax;
                o[6] = n2f*sxz - n1f*ay;  o[7] = n2f*syz + n1f*ax;  o[8] = n0f*c + n2f*szz;
            }
        }
    }
}

// ---------------------------------------------------------------- launch
extern "C" void kernel_launch(void* const* d_in, const int* in_sizes, int n_in,
                              void* d_out, int out_size, void* d_ws, size_t ws_size,
                              hipStream_t stream)
{
    (void)in_sizes; (void)n_in; (void)out_size; (void)ws_size;
    const int*   z      = (const int*)  d_in[0];
    const int*   ei     = (const int*)  d_in[1];
    const float* ew     = (const float*)d_in[2];
    const float* evn    = (const float*)d_in[3];
    const float* attr   = (const float*)d_in[4];
    const float* emb    = (const float*)d_in[5];
    const float* W_emb2 = (const float*)d_in[6];
    const float* b_emb2 = (const float*)d_in[7];
    const float* Wd1 = (const float*)d_in[8];  const float* bd1 = (const float*)d_in[9];
    const float* Wd2 = (const float*)d_in[10]; const float* bd2 = (const float*)d_in[11];
    const float* Wd3 = (const float*)d_in[12]; const float* bd3 = (const float*)d_in[13];
    const float* Wt1 = (const float*)d_in[14]; const float* Wt2 = (const float*)d_in[15];
    const float* Wt3 = (const float*)d_in[16];
    const float* Ws1 = (const float*)d_in[17]; const float* bs1 = (const float*)d_in[18];
    const float* Ws2 = (const float*)d_in[19]; const float* bs2 = (const float*)d_in[20];
    const float* ln_g = (const float*)d_in[21]; const float* ln_b = (const float*)d_in[22];
    float* out = (float*)d_out;

    char* ws = (char*)d_ws;
    size_t o = 0;
    auto take = [&](size_t b)->size_t{ size_t c = o; o += (b + 255) & ~(size_t)255; return c; };
    size_t acc_o = take((size_t)10 * NP * HID * 2);
    size_t ln_of = take((size_t)NP * HID * 2);
    size_t eL_o  = take((size_t)128 * HID * 4);
    size_t eR_o  = take((size_t)128 * HID * 4);
    size_t cnt_o = take((size_t)NN * 4);
    size_t off_o = take((size_t)(NN + 1) * 4);
    size_t cur_o = take((size_t)NN * 4);
    size_t el_o  = take((size_t)NE * 4);
    size_t met_o = take((size_t)NE * 8);
    size_t evp_o = take((size_t)NE * 12);
    size_t wc_o  = take((size_t)384 * 64 * 2);
    size_t wt_o  = take((size_t)3 * 128 * 128 * 2);
    size_t w1_o  = take((size_t)256 * 128 * 2);
    size_t w2_o  = take((size_t)384 * 256 * 2);
    size_t bdc_o = take((size_t)384 * 4);

    bf16_t* accb = (bf16_t*)(ws + acc_o);
    bf16_t* lnb  = (bf16_t*)(ws + ln_of);
    float* embL = (float*)(ws + eL_o);
    float* embR = (float*)(ws + eR_o);
    int* counts = (int*)(ws + cnt_o);
    int* offs   = (int*)(ws + off_o);
    int* cursor = (int*)(ws + cur_o);
    int* elist  = (int*)(ws + el_o);
    float2* meta = (float2*)(ws + met_o);
    float* evn_p = (float*)(ws + evp_o);
    bf16_t* Wcat = (bf16_t*)(ws + wc_o);
    bf16_t* Wtc  = (bf16_t*)(ws + wt_o);
    bf16_t* Ws1b = (bf16_t*)(ws + w1_o);
    bf16_t* Ws2b = (bf16_t*)(ws + w2_o);
    float* bdcat = (float*)(ws + bdc_o);

    hipMemsetAsync(counts, 0, (size_t)NN * 4, stream);

    k_prep <<<228, 256, 0, stream>>>(Wd1, Wd2, Wd3, bd1, bd2, bd3,
                                     Wt1, Wt2, Wt3, Ws1, Ws2, W_emb2, emb,
                                     Wcat, Wtc, Ws1b, Ws2b, bdcat, embL, embR);
    k_count<<<(NE + 255) / 256, 256, 0, stream>>>(ei, counts);
    k_scan <<<1, 1024, 0, stream>>>(counts, offs, cursor);
    k_fill <<<(NE + 255) / 256, 256, 0, stream>>>(ei, z, ew, evn, cursor, elist, meta, evn_p);
    k_edge_gather<<<NN, 256, 0, stream>>>(offs, elist, meta, evn_p, attr,
                                          Wcat, bdcat, embL, embR, b_emb2,
                                          ln_g, ln_b, accb, lnb);
    k_node <<<(NN + 15) / 16, 256, 0, stream>>>(lnb, accb, Ws1b, bs1, Ws2b, bs2, Wtc, out);
}